// Round 7
// baseline (283.157 us; speedup 1.0000x reference)
//
#include <hip/hip_runtime.h>
#include <hip/hip_bf16.h>

// Shapes fixed by the reference: T=1024, B=8, D=1024, H=16, DH=64. M=T*B=8192.
// Intermediate layouts: hq,hk = (B,H,T,DH) bf16; hvt = (B,H,DH,T) bf16 (V^T);
// vec = row-major (M,1024) bf16 with m = t*8+b.
// Scores are produced in log2-domain: 0.125*log2(e) folded into Wq.

typedef __bf16 bf16x8 __attribute__((ext_vector_type(8)));
typedef float f32x4 __attribute__((ext_vector_type(4)));
typedef float f32x16 __attribute__((ext_vector_type(16)));
typedef unsigned short ushort8_t __attribute__((ext_vector_type(8)));

__device__ __forceinline__ unsigned short f2bf(float f) {
  unsigned int u = __builtin_bit_cast(unsigned int, f);
  u += 0x7FFFu + ((u >> 16) & 1u);   // RNE; finite inputs
  return (unsigned short)(u >> 16);
}

__device__ __forceinline__ unsigned int cvt_pk_bf16(float lo, float hi) {
  unsigned int r;
  asm("v_cvt_pk_bf16_f32 %0, %1, %2" : "=v"(r) : "v"(lo), "v"(hi));
  return r;
}

__device__ __forceinline__ void gl2lds16(const unsigned short* g, unsigned short* l) {
  __builtin_amdgcn_global_load_lds(
      (const __attribute__((address_space(1))) void*)g,
      (__attribute__((address_space(3))) void*)l, 16, 0, 0);
}

// ---------------- bf16 GEMM, m97 structure + LDS double-buffer ---------------
// A: [8192][1024] bf16 row-major. Bt: [1024][1024] bf16 = W^T ([n][k]).
// EPI 1: bf16 out at ((b*16+h)*64+dh)*1024+t   (B,H,DH,T)  [V^T]
// EPI 2: fp32 out row-major [8192][1024]
template<int EPI>
__global__ __launch_bounds__(256)
void gemm_bf16(const unsigned short* __restrict__ A,
               const unsigned short* __restrict__ Bt,
               void* __restrict__ C)
{
  __shared__ __align__(16) unsigned short As[2][128 * 64];
  __shared__ __align__(16) unsigned short Bs[2][128 * 64];
  const int tid = threadIdx.x;
  const int lane = tid & 63, wid = tid >> 6;
  const int wr = wid >> 1, wc = wid & 1;
  const int l15 = lane & 15, l4 = lane >> 4;
  const int bm = blockIdx.x, bn = blockIdx.y;

  f32x4 acc[4][4];
#pragma unroll
  for (int m = 0; m < 4; ++m)
#pragma unroll
    for (int n = 0; n < 4; ++n)
      acc[m][n] = (f32x4){0.f, 0.f, 0.f, 0.f};

  const unsigned short* ga = A  + (size_t)bm * 128 * 1024 + (tid >> 3) * 1024 + (tid & 7) * 8;
  const unsigned short* gb = Bt + (size_t)bn * 128 * 1024 + (tid >> 3) * 1024 + (tid & 7) * 8;
  const int ldsoff = wid * 512;   // wave-uniform LDS base; HW adds lane*16B

#pragma unroll
  for (int i = 0; i < 4; ++i) {
    gl2lds16(ga + i * 32 * 1024, &As[0][ldsoff + i * 2048]);
    gl2lds16(gb + i * 32 * 1024, &Bs[0][ldsoff + i * 2048]);
  }

  int cur = 0;
  for (int kt = 0; kt < 1024; kt += 64) {
    __syncthreads();   // buf[cur] staged (implicit vmcnt drain) + prev compute done
    if (kt + 64 < 1024) {
#pragma unroll
      for (int i = 0; i < 4; ++i) {
        gl2lds16(ga + i * 32 * 1024 + kt + 64, &As[cur ^ 1][ldsoff + i * 2048]);
        gl2lds16(gb + i * 32 * 1024 + kt + 64, &Bs[cur ^ 1][ldsoff + i * 2048]);
      }
    }
#pragma unroll
    for (int kk = 0; kk < 2; ++kk) {
      bf16x8 af[4], bfr[4];
#pragma unroll
      for (int m = 0; m < 4; ++m)
        af[m] = *(const bf16x8*)(&As[cur][(wr * 64 + m * 16 + l15) * 64 + kk * 32 + l4 * 8]);
#pragma unroll
      for (int n = 0; n < 4; ++n)
        bfr[n] = *(const bf16x8*)(&Bs[cur][(wc * 64 + n * 16 + l15) * 64 + kk * 32 + l4 * 8]);
#pragma unroll
      for (int m = 0; m < 4; ++m)
#pragma unroll
        for (int n = 0; n < 4; ++n)
          acc[m][n] = __builtin_amdgcn_mfma_f32_16x16x32_bf16(af[m], bfr[n], acc[m][n], 0, 0, 0);
    }
    cur ^= 1;
  }

#pragma unroll
  for (int m = 0; m < 4; ++m)
#pragma unroll
    for (int n = 0; n < 4; ++n)
#pragma unroll
      for (int r = 0; r < 4; ++r) {
        int row = bm * 128 + wr * 64 + m * 16 + l4 * 4 + r;   // m = t*8+b
        int col = bn * 128 + wc * 64 + n * 16 + l15;           // h*64+dh
        float v = acc[m][n][r];
        if constexpr (EPI == 2) {
          ((float*)C)[(size_t)row * 1024 + col] = v;
        } else {
          int t = row >> 3, b = row & 7;
          int h = col >> 6, dh = col & 63;
          size_t base = ((size_t)(b * 16 + h)) << 16;
          ((unsigned short*)C)[base + (size_t)dh * 1024 + t] = f2bf(v);
        }
      }
}

// ---------------- Q+K combined GEMM (single-buffer, 1024 blocks) -------------
// z=0: Aq x Wq -> Cq ; z=1: Ak x Wk -> Ck. Output (B,H,T,DH) bf16.
__global__ __launch_bounds__(256)
void gemm_qk(const unsigned short* __restrict__ Aq, const unsigned short* __restrict__ Ak,
             const unsigned short* __restrict__ Wq, const unsigned short* __restrict__ Wk,
             unsigned short* __restrict__ Cq, unsigned short* __restrict__ Ck)
{
  const int z = blockIdx.z;
  const unsigned short* A  = z ? Ak : Aq;
  const unsigned short* Bt = z ? Wk : Wq;
  unsigned short* C        = z ? Ck : Cq;
  __shared__ __align__(16) unsigned short As[128 * 64];
  __shared__ __align__(16) unsigned short Bs[128 * 64];
  const int tid = threadIdx.x;
  const int lane = tid & 63, wid = tid >> 6;
  const int wr = wid >> 1, wc = wid & 1;
  const int l15 = lane & 15, l4 = lane >> 4;
  const int bm = blockIdx.x, bn = blockIdx.y;

  f32x4 acc[4][4];
#pragma unroll
  for (int m = 0; m < 4; ++m)
#pragma unroll
    for (int n = 0; n < 4; ++n)
      acc[m][n] = (f32x4){0.f, 0.f, 0.f, 0.f};

  const unsigned short* ga = A  + (size_t)bm * 128 * 1024 + (tid >> 3) * 1024 + (tid & 7) * 8;
  const unsigned short* gb = Bt + (size_t)bn * 128 * 1024 + (tid >> 3) * 1024 + (tid & 7) * 8;
  unsigned short* la = As + wid * 512;
  unsigned short* lb = Bs + wid * 512;

  for (int kt = 0; kt < 1024; kt += 64) {
    if (kt) __syncthreads();
#pragma unroll
    for (int i = 0; i < 4; ++i) {
      gl2lds16(ga + i * 32 * 1024 + kt, la + i * 2048);
      gl2lds16(gb + i * 32 * 1024 + kt, lb + i * 2048);
    }
    __syncthreads();
#pragma unroll
    for (int kk = 0; kk < 2; ++kk) {
      bf16x8 af[4], bfr[4];
#pragma unroll
      for (int m = 0; m < 4; ++m)
        af[m] = *(const bf16x8*)(As + (wr * 64 + m * 16 + l15) * 64 + kk * 32 + l4 * 8);
#pragma unroll
      for (int n = 0; n < 4; ++n)
        bfr[n] = *(const bf16x8*)(Bs + (wc * 64 + n * 16 + l15) * 64 + kk * 32 + l4 * 8);
#pragma unroll
      for (int m = 0; m < 4; ++m)
#pragma unroll
        for (int n = 0; n < 4; ++n)
          acc[m][n] = __builtin_amdgcn_mfma_f32_16x16x32_bf16(af[m], bfr[n], acc[m][n], 0, 0, 0);
    }
  }

#pragma unroll
  for (int m = 0; m < 4; ++m)
#pragma unroll
    for (int n = 0; n < 4; ++n)
#pragma unroll
      for (int r = 0; r < 4; ++r) {
        int row = bm * 128 + wr * 64 + m * 16 + l4 * 4 + r;   // m = t*8+b
        int col = bn * 128 + wc * 64 + n * 16 + l15;           // h*64+dh
        int t = row >> 3, b = row & 7;
        int h = col >> 6, dh = col & 63;
        size_t base = ((size_t)(b * 16 + h)) << 16;
        C[base + (size_t)t * 64 + dh] = f2bf(acc[m][n][r]);
      }
}

// ---------------- fp32 -> bf16 converts ----------------
__global__ __launch_bounds__(256)
void conv_bf16(const float* __restrict__ in, unsigned short* __restrict__ out)
{
  size_t i = ((size_t)blockIdx.x * 256 + threadIdx.x) * 8;
  float4 a = *(const float4*)(in + i);
  float4 b = *(const float4*)(in + i + 4);
  ushort8_t o;
  o[0] = f2bf(a.x); o[1] = f2bf(a.y); o[2] = f2bf(a.z); o[3] = f2bf(a.w);
  o[4] = f2bf(b.x); o[5] = f2bf(b.y); o[6] = f2bf(b.z); o[7] = f2bf(b.w);
  *(ushort8_t*)(out + i) = o;
}

__global__ __launch_bounds__(256)
void conv2_bf16(const float* __restrict__ in0, const float* __restrict__ in1,
                unsigned short* __restrict__ out0, unsigned short* __restrict__ out1)
{
  const float* in = blockIdx.y ? in1 : in0;
  unsigned short* out = blockIdx.y ? out1 : out0;
  size_t i = ((size_t)blockIdx.x * 256 + threadIdx.x) * 8;
  float4 a = *(const float4*)(in + i);
  float4 b = *(const float4*)(in + i + 4);
  ushort8_t o;
  o[0] = f2bf(a.x); o[1] = f2bf(a.y); o[2] = f2bf(a.z); o[3] = f2bf(a.w);
  o[4] = f2bf(b.x); o[5] = f2bf(b.y); o[6] = f2bf(b.z); o[7] = f2bf(b.w);
  *(ushort8_t*)(out + i) = o;
}

// -------- weights: W[k][n] fp32 -> Wt[n][k] bf16 (x4, y-selected) -----------
__global__ __launch_bounds__(256)
void wconv4(const float* __restrict__ W0, const float* __restrict__ W1,
            const float* __restrict__ W2, const float* __restrict__ W3,
            unsigned short* __restrict__ T0, unsigned short* __restrict__ T1,
            unsigned short* __restrict__ T2, unsigned short* __restrict__ T3)
{
  const int y = blockIdx.y;
  const float* W = y == 0 ? W0 : y == 1 ? W1 : y == 2 ? W2 : W3;
  unsigned short* Wt = y == 0 ? T0 : y == 1 ? T1 : y == 2 ? T2 : T3;
  // fold 1/sqrt(DH)*log2(e) into Wq -> scores in log2 domain
  const float scale = (y == 0) ? 0.125f * 1.44269504088896f : 1.0f;
  int id = blockIdx.x * 256 + threadIdx.x;
  int n = id & 1023;
  int k0 = (id >> 10) << 3;
  ushort8_t o;
#pragma unroll
  for (int j = 0; j < 8; ++j)
    o[j] = f2bf(W[(size_t)(k0 + j) * 1024 + n] * scale);
  *(ushort8_t*)(Wt + (size_t)n * 1024 + k0) = o;
}

// ---------------- causal flash attention (swapped 32x32 MFMA, no LDS) -------
// 1024 blocks x 256 threads. Block owns head bh and q-group j; its 4 waves
// take BALANCED q-tiles tau in {j, 15-j, 16+j, 31-j} (rotated by j) so every
// block -- hence every CU -- does equal total work (34 chunk-iters/block).
// S^T = K*Q^T  -> lane holds scores of q-row (lane&31)     [C: col=lane&31]
// O^T = V^T*P^T -> lane holds O columns for same q-row     [alpha lane-local]
// PV uses k-slot permutation pi(s2,h,j)=(j&3)+8*(2*s2+(j>>2))+4h on BOTH
// operands; V-tile loads are issued BEFORE QK^T so softmax covers their latency.
// NOTE: wave-half reductions use __shfl_xor(x,32); the permlane32_swap form
// with two copies of one value is register-coalescing-unsafe (round-6 bug).
__global__ __launch_bounds__(256)
void flash_attn(const unsigned short* __restrict__ hq,
                const unsigned short* __restrict__ hk,
                const unsigned short* __restrict__ hvt,
                unsigned short* __restrict__ vec)
{
  const int tid = threadIdx.x;
  const int lane = tid & 63, wid = tid >> 6;
  const int l31 = lane & 31, h = lane >> 5;
  const int h8 = h * 8, h4 = h * 4;
  // XCD swizzle: all 8 q-group blocks of a head on one XCD.
  const int bid = blockIdx.x;
  const int xcd = bid & 7;
  const int i = bid >> 3;            // 0..127
  const int bh = (xcd << 4) | (i & 15);
  const int j = i >> 4;              // 0..7
  const int idx = (wid + j) & 3;
  const int tau = idx == 0 ? j : idx == 1 ? 15 - j : idx == 2 ? 16 + j : 31 - j;
  const int b = bh >> 4, hh = bh & 15;
  const size_t base = (size_t)bh << 16;
  const int t0 = tau * 32;
  const int qrow = t0 + l31;

  // Q as B-fragments (col=q=lane&31, k=d=16*ks+8h+jj), log2-scale pre-folded
  bf16x8 qf[4];
#pragma unroll
  for (int ks = 0; ks < 4; ++ks)
    qf[ks] = *(const bf16x8*)(hq + base + (size_t)qrow * 64 + ks * 16 + h8);

  f32x16 of0, of1;
#pragma unroll
  for (int r = 0; r < 16; ++r) { of0[r] = 0.f; of1[r] = 0.f; }
  float mrun = -3.0e38f, lrun = 0.f;

  const int nchunks = (tau >> 1) + 1;   // 64-kv chunks to diagonal
  for (int kt = 0; kt < nchunks; ++kt) {
    const int kvb = kt * 64;
    // ---- issue V loads early; consumed after softmax (latency covered) ----
    uint2 vld[4][4];
#pragma unroll
    for (int s2 = 0; s2 < 4; ++s2) {
      const unsigned short* pv0 = hvt + base + (size_t)l31 * 1024 + kvb + s2 * 16 + h4;
      const unsigned short* pv1 = pv0 + 32 * 1024;
      vld[s2][0] = *(const uint2*)(pv0);
      vld[s2][1] = *(const uint2*)(pv0 + 8);
      vld[s2][2] = *(const uint2*)(pv1);
      vld[s2][3] = *(const uint2*)(pv1 + 8);
    }
    // ---- S^T: two 32-kv subtiles, independent accumulator chains ----
    f32x16 sa, sb;
#pragma unroll
    for (int r = 0; r < 16; ++r) { sa[r] = 0.f; sb[r] = 0.f; }
    __builtin_amdgcn_s_setprio(1);
#pragma unroll
    for (int ks = 0; ks < 4; ++ks) {
      bf16x8 kfa = *(const bf16x8*)(hk + base + (size_t)(kvb + l31) * 64      + ks * 16 + h8);
      bf16x8 kfb = *(const bf16x8*)(hk + base + (size_t)(kvb + 32 + l31) * 64 + ks * 16 + h8);
      sa = __builtin_amdgcn_mfma_f32_32x32x16_bf16(kfa, qf[ks], sa, 0, 0, 0);
      sb = __builtin_amdgcn_mfma_f32_32x32x16_bf16(kfb, qf[ks], sb, 0, 0, 0);
    }
    __builtin_amdgcn_s_setprio(0);
    // causal mask on the diagonal chunk only; kv = kvb(+32) + (r&3)+8*(r>>2)+4h
    if (kt == nchunks - 1) {
#pragma unroll
      for (int r = 0; r < 16; ++r) {
        int kv = kvb + (r & 3) + 8 * (r >> 2) + h4;
        if (kv > qrow) sa[r] = -1.0e30f;
        if (kv + 32 > qrow) sb[r] = -1.0e30f;
      }
    }
    // ---- online softmax in log2 domain; row = lane&31 (+ lane^32 half) ----
    float mx[8];
#pragma unroll
    for (int g = 0; g < 4; ++g) {
      mx[g]     = fmaxf(fmaxf(sa[4 * g], sa[4 * g + 1]), fmaxf(sa[4 * g + 2], sa[4 * g + 3]));
      mx[4 + g] = fmaxf(fmaxf(sb[4 * g], sb[4 * g + 1]), fmaxf(sb[4 * g + 2], sb[4 * g + 3]));
    }
    mx[0] = fmaxf(mx[0], mx[1]); mx[2] = fmaxf(mx[2], mx[3]);
    mx[4] = fmaxf(mx[4], mx[5]); mx[6] = fmaxf(mx[6], mx[7]);
    float mloc = fmaxf(fmaxf(mx[0], mx[2]), fmaxf(mx[4], mx[6]));
    mloc = fmaxf(mloc, __shfl_xor(mloc, 32));
    // defer-max (T13, THR=8 in log2 units): skip O/l rescale if growth small
    if (!__all(mloc <= mrun + 8.0f)) {
      float mnew = fmaxf(mrun, mloc);
      float alpha = __builtin_amdgcn_exp2f(mrun - mnew);
      mrun = mnew;
      lrun *= alpha;
#pragma unroll
      for (int r = 0; r < 16; ++r) { of0[r] *= alpha; of1[r] *= alpha; }
    }
    // ---- P = exp2(S - m), packed per 16-kv slice into B-fragments ----
    bf16x8 pa[4];
    float lsum = 0.f;
#pragma unroll
    for (int s2 = 0; s2 < 4; ++s2) {
      float p0 = __builtin_amdgcn_exp2f(((s2 < 2) ? sa[8 * s2 + 0] : sb[8 * (s2 - 2) + 0]) - mrun);
      float p1 = __builtin_amdgcn_exp2f(((s2 < 2) ? sa[8 * s2 + 1] : sb[8 * (s2 - 2) + 1]) - mrun);
      float p2 = __builtin_amdgcn_exp2f(((s2 < 2) ? sa[8 * s2 + 2] : sb[8 * (s2 - 2) + 2]) - mrun);
      float p3 = __builtin_amdgcn_exp2f(((s2 < 2) ? sa[8 * s2 + 3] : sb[8 * (s2 - 2) + 3]) - mrun);
      float p4 = __builtin_amdgcn_exp2f(((s2 < 2) ? sa[8 * s2 + 4] : sb[8 * (s2 - 2) + 4]) - mrun);
      float p5 = __builtin_amdgcn_exp2f(((s2 < 2) ? sa[8 * s2 + 5] : sb[8 * (s2 - 2) + 5]) - mrun);
      float p6 = __builtin_amdgcn_exp2f(((s2 < 2) ? sa[8 * s2 + 6] : sb[8 * (s2 - 2) + 6]) - mrun);
      float p7 = __builtin_amdgcn_exp2f(((s2 < 2) ? sa[8 * s2 + 7] : sb[8 * (s2 - 2) + 7]) - mrun);
      lsum += (p0 + p1) + (p2 + p3) + ((p4 + p5) + (p6 + p7));
      uint4 w4 = make_uint4(cvt_pk_bf16(p0, p1), cvt_pk_bf16(p2, p3),
                            cvt_pk_bf16(p4, p5), cvt_pk_bf16(p6, p7));
      pa[s2] = __builtin_bit_cast(bf16x8, w4);
    }
    lsum += __shfl_xor(lsum, 32);
    lrun += lsum;
    // ---- O^T += V^T * P^T with permuted k-slots on both operands ----
    __builtin_amdgcn_s_setprio(1);
#pragma unroll
    for (int s2 = 0; s2 < 4; ++s2) {
      bf16x8 vf0 = __builtin_bit_cast(bf16x8,
          make_uint4(vld[s2][0].x, vld[s2][0].y, vld[s2][1].x, vld[s2][1].y));
      bf16x8 vf1 = __builtin_bit_cast(bf16x8,
          make_uint4(vld[s2][2].x, vld[s2][2].y, vld[s2][3].x, vld[s2][3].y));
      of0 = __builtin_amdgcn_mfma_f32_32x32x16_bf16(vf0, pa[s2], of0, 0, 0, 0);
      of1 = __builtin_amdgcn_mfma_f32_32x32x16_bf16(vf1, pa[s2], of1, 0, 0, 0);
    }
    __builtin_amdgcn_s_setprio(0);
  }

  // ---- write vec: lane owns q-row; d = 8g + 4h + rr (of0), +32 (of1) ----
  float rl = __builtin_amdgcn_rcpf(lrun);
  unsigned short* vout = vec + ((size_t)qrow * 8 + b) * 1024 + hh * 64;
#pragma unroll
  for (int g = 0; g < 4; ++g) {
    ushort4 o;
    o.x = f2bf(of0[g * 4 + 0] * rl); o.y = f2bf(of0[g * 4 + 1] * rl);
    o.z = f2bf(of0[g * 4 + 2] * rl); o.w = f2bf(of0[g * 4 + 3] * rl);
    *(ushort4*)(vout + 8 * g + h4) = o;
    o.x = f2bf(of1[g * 4 + 0] * rl); o.y = f2bf(of1[g * 4 + 1] * rl);
    o.z = f2bf(of1[g * 4 + 2] * rl); o.w = f2bf(of1[g * 4 + 3] * rl);
    *(ushort4*)(vout + 32 + 8 * g + h4) = o;
  }
}

// ---------------- in-place LayerNorm over rows of 1024 fp32 ----------------
__global__ __launch_bounds__(256)
void ln_inplace(float* __restrict__ x, const float* __restrict__ gamma,
                const float* __restrict__ beta)
{
  __shared__ float red[2][4];
  const int tid = threadIdx.x;
  const int lane = tid & 63, wid = tid >> 6;
  const size_t row = blockIdx.x;
  float4 v = *(const float4*)(x + row * 1024 + tid * 4);
  float s = v.x + v.y + v.z + v.w;
  float q = v.x * v.x + v.y * v.y + v.z * v.z + v.w * v.w;
#pragma unroll
  for (int m = 1; m <= 32; m <<= 1) {
    s += __shfl_xor(s, m);
    q += __shfl_xor(q, m);
  }
  if (lane == 0) { red[0][wid] = s; red[1][wid] = q; }
  __syncthreads();
  float ts = red[0][0] + red[0][1] + red[0][2] + red[0][3];
  float tq = red[1][0] + red[1][1] + red[1][2] + red[1][3];
  float mu = ts * (1.0f / 1024.0f);
  float var = tq * (1.0f / 1024.0f) - mu * mu;
  float rs = rsqrtf(var + 1e-5f);
  float4 g  = *(const float4*)(gamma + tid * 4);
  float4 bt = *(const float4*)(beta + tid * 4);
  v.x = (v.x - mu) * rs * g.x + bt.x;
  v.y = (v.y - mu) * rs * g.y + bt.y;
  v.z = (v.z - mu) * rs * g.z + bt.z;
  v.w = (v.w - mu) * rs * g.w + bt.w;
  *(float4*)(x + row * 1024 + tid * 4) = v;
}

extern "C" void kernel_launch(void* const* d_in, const int* in_sizes, int n_in,
                              void* d_out, int out_size, void* d_ws, size_t ws_size,
                              hipStream_t stream) {
  const float* q     = (const float*)d_in[0];
  const float* k     = (const float*)d_in[1];
  const float* v     = (const float*)d_in[2];
  // d_in[3] = attn_mask (causal) -- analytic in-kernel
  const float* Wq    = (const float*)d_in[4];
  const float* Wk    = (const float*)d_in[5];
  const float* Wv    = (const float*)d_in[6];
  const float* Wo    = (const float*)d_in[7];
  const float* gamma = (const float*)d_in[8];
  const float* beta  = (const float*)d_in[9];

  unsigned short* ws = (unsigned short*)d_ws;
  const size_t MSZ = (size_t)8192 * 1024;
  unsigned short* hq   = ws;                 // (B,H,T,DH)
  unsigned short* hk   = ws + MSZ;           // (B,H,T,DH)
  unsigned short* hvt  = ws + 2 * MSZ;       // (B,H,DH,T)
  unsigned short* tmp  = ws + 3 * MSZ;       // v-bf16, then k-bf16
  unsigned short* qb16 = ws + 4 * MSZ;       // q-bf16, then vec
  unsigned short* WqT  = ws + 5 * MSZ;       // 4x [1024][1024] bf16
  unsigned short* WkT  = WqT + 1048576;
  unsigned short* WvT  = WqT + 2097152;
  unsigned short* WoT  = WqT + 3145728;
  float* out = (float*)d_out;

  dim3 bb(256);
  dim3 gg(64, 8);
  wconv4<<<dim3(512, 4), bb, 0, stream>>>(Wq, Wk, Wv, Wo, WqT, WkT, WvT, WoT);

  conv_bf16<<<4096, bb, 0, stream>>>(v, tmp);
  gemm_bf16<1><<<gg, bb, 0, stream>>>(tmp, WvT, hvt);           // V^T

  conv2_bf16<<<dim3(4096, 2), bb, 0, stream>>>(q, k, qb16, tmp);
  gemm_qk<<<dim3(64, 8, 2), bb, 0, stream>>>(qb16, tmp, WqT, WkT, hq, hk);

  flash_attn<<<1024, bb, 0, stream>>>(hq, hk, hvt, qb16);       // vec = qb16

  gemm_bf16<2><<<gg, bb, 0, stream>>>(qb16, WoT, out);
  ln_inplace<<<8192, bb, 0, stream>>>(out, gamma, beta);
}

// Round 8
// 210.593 us; speedup vs baseline: 1.3446x; 1.3446x over previous
//
#include <hip/hip_runtime.h>
#include <hip/hip_bf16.h>

// Shapes fixed by the reference: T=1024, B=8, D=1024, H=16, DH=64. M=T*B=8192.
// Intermediate layouts: hq,hk = (B,H,T,DH) bf16; hvt = (B,H,DH,T) bf16 (V^T);
// vec = row-major (M,1024) bf16 with m = t*8+b.
// Scores are produced in log2-domain: 0.125*log2(e) folded into Wq.

typedef __bf16 bf16x8 __attribute__((ext_vector_type(8)));
typedef float f32x4 __attribute__((ext_vector_type(4)));
typedef float f32x16 __attribute__((ext_vector_type(16)));
typedef unsigned short ushort8_t __attribute__((ext_vector_type(8)));

__device__ __forceinline__ unsigned short f2bf(float f) {
  unsigned int u = __builtin_bit_cast(unsigned int, f);
  u += 0x7FFFu + ((u >> 16) & 1u);   // RNE; finite inputs
  return (unsigned short)(u >> 16);
}

__device__ __forceinline__ unsigned int cvt_pk_bf16(float lo, float hi) {
  unsigned int r;
  asm("v_cvt_pk_bf16_f32 %0, %1, %2" : "=v"(r) : "v"(lo), "v"(hi));
  return r;
}

__device__ __forceinline__ void gl2lds16(const unsigned short* g, unsigned short* l) {
  __builtin_amdgcn_global_load_lds(
      (const __attribute__((address_space(1))) void*)g,
      (__attribute__((address_space(3))) void*)l, 16, 0, 0);
}

// ---------------- bf16 GEMM, m97 structure + LDS double-buffer ---------------
// A: [8192][1024] bf16 row-major. Bt: [1024][1024] bf16 = W^T ([n][k]).
// EPI 1: bf16 out at ((b*16+h)*64+dh)*1024+t   (B,H,DH,T)  [V^T]
// EPI 2: fp32 out row-major [8192][1024]
template<int EPI>
__global__ __launch_bounds__(256)
void gemm_bf16(const unsigned short* __restrict__ A,
               const unsigned short* __restrict__ Bt,
               void* __restrict__ C)
{
  __shared__ __align__(16) unsigned short As[2][128 * 64];
  __shared__ __align__(16) unsigned short Bs[2][128 * 64];
  const int tid = threadIdx.x;
  const int lane = tid & 63, wid = tid >> 6;
  const int wr = wid >> 1, wc = wid & 1;
  const int l15 = lane & 15, l4 = lane >> 4;
  const int bm = blockIdx.x, bn = blockIdx.y;

  f32x4 acc[4][4];
#pragma unroll
  for (int m = 0; m < 4; ++m)
#pragma unroll
    for (int n = 0; n < 4; ++n)
      acc[m][n] = (f32x4){0.f, 0.f, 0.f, 0.f};

  const unsigned short* ga = A  + (size_t)bm * 128 * 1024 + (tid >> 3) * 1024 + (tid & 7) * 8;
  const unsigned short* gb = Bt + (size_t)bn * 128 * 1024 + (tid >> 3) * 1024 + (tid & 7) * 8;
  const int ldsoff = wid * 512;   // wave-uniform LDS base; HW adds lane*16B

#pragma unroll
  for (int i = 0; i < 4; ++i) {
    gl2lds16(ga + i * 32 * 1024, &As[0][ldsoff + i * 2048]);
    gl2lds16(gb + i * 32 * 1024, &Bs[0][ldsoff + i * 2048]);
  }

  int cur = 0;
  for (int kt = 0; kt < 1024; kt += 64) {
    __syncthreads();   // buf[cur] staged (implicit vmcnt drain) + prev compute done
    if (kt + 64 < 1024) {
#pragma unroll
      for (int i = 0; i < 4; ++i) {
        gl2lds16(ga + i * 32 * 1024 + kt + 64, &As[cur ^ 1][ldsoff + i * 2048]);
        gl2lds16(gb + i * 32 * 1024 + kt + 64, &Bs[cur ^ 1][ldsoff + i * 2048]);
      }
    }
#pragma unroll
    for (int kk = 0; kk < 2; ++kk) {
      bf16x8 af[4], bfr[4];
#pragma unroll
      for (int m = 0; m < 4; ++m)
        af[m] = *(const bf16x8*)(&As[cur][(wr * 64 + m * 16 + l15) * 64 + kk * 32 + l4 * 8]);
#pragma unroll
      for (int n = 0; n < 4; ++n)
        bfr[n] = *(const bf16x8*)(&Bs[cur][(wc * 64 + n * 16 + l15) * 64 + kk * 32 + l4 * 8]);
#pragma unroll
      for (int m = 0; m < 4; ++m)
#pragma unroll
        for (int n = 0; n < 4; ++n)
          acc[m][n] = __builtin_amdgcn_mfma_f32_16x16x32_bf16(af[m], bfr[n], acc[m][n], 0, 0, 0);
    }
    cur ^= 1;
  }

#pragma unroll
  for (int m = 0; m < 4; ++m)
#pragma unroll
    for (int n = 0; n < 4; ++n)
#pragma unroll
      for (int r = 0; r < 4; ++r) {
        int row = bm * 128 + wr * 64 + m * 16 + l4 * 4 + r;   // m = t*8+b
        int col = bn * 128 + wc * 64 + n * 16 + l15;           // h*64+dh
        float v = acc[m][n][r];
        if constexpr (EPI == 2) {
          ((float*)C)[(size_t)row * 1024 + col] = v;
        } else {
          int t = row >> 3, b = row & 7;
          int h = col >> 6, dh = col & 63;
          size_t base = ((size_t)(b * 16 + h)) << 16;
          ((unsigned short*)C)[base + (size_t)dh * 1024 + t] = f2bf(v);
        }
      }
}

// ---------------- Q+K combined GEMM (single-buffer, 1024 blocks) -------------
__global__ __launch_bounds__(256)
void gemm_qk(const unsigned short* __restrict__ Aq, const unsigned short* __restrict__ Ak,
             const unsigned short* __restrict__ Wq, const unsigned short* __restrict__ Wk,
             unsigned short* __restrict__ Cq, unsigned short* __restrict__ Ck)
{
  const int z = blockIdx.z;
  const unsigned short* A  = z ? Ak : Aq;
  const unsigned short* Bt = z ? Wk : Wq;
  unsigned short* C        = z ? Ck : Cq;
  __shared__ __align__(16) unsigned short As[128 * 64];
  __shared__ __align__(16) unsigned short Bs[128 * 64];
  const int tid = threadIdx.x;
  const int lane = tid & 63, wid = tid >> 6;
  const int wr = wid >> 1, wc = wid & 1;
  const int l15 = lane & 15, l4 = lane >> 4;
  const int bm = blockIdx.x, bn = blockIdx.y;

  f32x4 acc[4][4];
#pragma unroll
  for (int m = 0; m < 4; ++m)
#pragma unroll
    for (int n = 0; n < 4; ++n)
      acc[m][n] = (f32x4){0.f, 0.f, 0.f, 0.f};

  const unsigned short* ga = A  + (size_t)bm * 128 * 1024 + (tid >> 3) * 1024 + (tid & 7) * 8;
  const unsigned short* gb = Bt + (size_t)bn * 128 * 1024 + (tid >> 3) * 1024 + (tid & 7) * 8;
  unsigned short* la = As + wid * 512;
  unsigned short* lb = Bs + wid * 512;

  for (int kt = 0; kt < 1024; kt += 64) {
    if (kt) __syncthreads();
#pragma unroll
    for (int i = 0; i < 4; ++i) {
      gl2lds16(ga + i * 32 * 1024 + kt, la + i * 2048);
      gl2lds16(gb + i * 32 * 1024 + kt, lb + i * 2048);
    }
    __syncthreads();
#pragma unroll
    for (int kk = 0; kk < 2; ++kk) {
      bf16x8 af[4], bfr[4];
#pragma unroll
      for (int m = 0; m < 4; ++m)
        af[m] = *(const bf16x8*)(As + (wr * 64 + m * 16 + l15) * 64 + kk * 32 + l4 * 8);
#pragma unroll
      for (int n = 0; n < 4; ++n)
        bfr[n] = *(const bf16x8*)(Bs + (wc * 64 + n * 16 + l15) * 64 + kk * 32 + l4 * 8);
#pragma unroll
      for (int m = 0; m < 4; ++m)
#pragma unroll
        for (int n = 0; n < 4; ++n)
          acc[m][n] = __builtin_amdgcn_mfma_f32_16x16x32_bf16(af[m], bfr[n], acc[m][n], 0, 0, 0);
    }
  }

#pragma unroll
  for (int m = 0; m < 4; ++m)
#pragma unroll
    for (int n = 0; n < 4; ++n)
#pragma unroll
      for (int r = 0; r < 4; ++r) {
        int row = bm * 128 + wr * 64 + m * 16 + l4 * 4 + r;   // m = t*8+b
        int col = bn * 128 + wc * 64 + n * 16 + l15;           // h*64+dh
        int t = row >> 3, b = row & 7;
        int h = col >> 6, dh = col & 63;
        size_t base = ((size_t)(b * 16 + h)) << 16;
        C[base + (size_t)t * 64 + dh] = f2bf(acc[m][n][r]);
      }
}

// ---------------- fp32 -> bf16 converts ----------------
__global__ __launch_bounds__(256)
void conv_bf16(const float* __restrict__ in, unsigned short* __restrict__ out)
{
  size_t i = ((size_t)blockIdx.x * 256 + threadIdx.x) * 8;
  float4 a = *(const float4*)(in + i);
  float4 b = *(const float4*)(in + i + 4);
  ushort8_t o;
  o[0] = f2bf(a.x); o[1] = f2bf(a.y); o[2] = f2bf(a.z); o[3] = f2bf(a.w);
  o[4] = f2bf(b.x); o[5] = f2bf(b.y); o[6] = f2bf(b.z); o[7] = f2bf(b.w);
  *(ushort8_t*)(out + i) = o;
}

__global__ __launch_bounds__(256)
void conv2_bf16(const float* __restrict__ in0, const float* __restrict__ in1,
                unsigned short* __restrict__ out0, unsigned short* __restrict__ out1)
{
  const float* in = blockIdx.y ? in1 : in0;
  unsigned short* out = blockIdx.y ? out1 : out0;
  size_t i = ((size_t)blockIdx.x * 256 + threadIdx.x) * 8;
  float4 a = *(const float4*)(in + i);
  float4 b = *(const float4*)(in + i + 4);
  ushort8_t o;
  o[0] = f2bf(a.x); o[1] = f2bf(a.y); o[2] = f2bf(a.z); o[3] = f2bf(a.w);
  o[4] = f2bf(b.x); o[5] = f2bf(b.y); o[6] = f2bf(b.z); o[7] = f2bf(b.w);
  *(ushort8_t*)(out + i) = o;
}

// -------- weights: W[k][n] fp32 -> Wt[n][k] bf16 (x4, y-selected) -----------
__global__ __launch_bounds__(256)
void wconv4(const float* __restrict__ W0, const float* __restrict__ W1,
            const float* __restrict__ W2, const float* __restrict__ W3,
            unsigned short* __restrict__ T0, unsigned short* __restrict__ T1,
            unsigned short* __restrict__ T2, unsigned short* __restrict__ T3)
{
  const int y = blockIdx.y;
  const float* W = y == 0 ? W0 : y == 1 ? W1 : y == 2 ? W2 : W3;
  unsigned short* Wt = y == 0 ? T0 : y == 1 ? T1 : y == 2 ? T2 : T3;
  const float scale = (y == 0) ? 0.125f * 1.44269504088896f : 1.0f;
  int id = blockIdx.x * 256 + threadIdx.x;
  int n = id & 1023;
  int k0 = (id >> 10) << 3;
  ushort8_t o;
#pragma unroll
  for (int j = 0; j < 8; ++j)
    o[j] = f2bf(W[(size_t)(k0 + j) * 1024 + n] * scale);
  *(ushort8_t*)(Wt + (size_t)n * 1024 + k0) = o;
}

// ---------------- causal flash attention (LDS-staged K/V, swapped 32x32) ----
// Block = (head bh, 128-row q-band qb); 4 waves = q-tiles tau = 4qb+wid.
// All waves share the chunk sequence; K tile (64x64) and V^T tile (64x64) are
// staged per chunk into double-buffered LDS via global_load_lds (coalesced),
// with the XOR swizzle (c16 ^= row&7) applied to the GLOBAL SOURCE (linear LDS
// dest, rule #21); ds_reads apply the same XOR -> bank spread.
// S^T = K*Q^T (lane owns q-row lane&31); O^T = V^T*P^T (alpha lane-local).
// PV k-slot permutation pi on both operands as in rounds 4-7.
__global__ __launch_bounds__(256)
void flash_attn(const unsigned short* __restrict__ hq,
                const unsigned short* __restrict__ hk,
                const unsigned short* __restrict__ hvt,
                unsigned short* __restrict__ vec)
{
  __shared__ __align__(16) unsigned short Ks[2][64 * 64];
  __shared__ __align__(16) unsigned short Vs[2][64 * 64];
  const int tid = threadIdx.x;
  const int lane = tid & 63, wid = tid >> 6;
  const int l31 = lane & 31, h = lane >> 5;
  const int h8 = h * 8, h4 = h * 4;
  const int swz = l31 & 7;             // read-side row XOR key
  // XCD swizzle: 8 q-band blocks of a head on one XCD; heavy (qb=7) first.
  const int bid = blockIdx.x;
  const int xcd = bid & 7;
  const int i = bid >> 3;              // 0..127
  const int bh = (xcd << 4) | (i & 15);
  const int qb = 7 - (i >> 4);         // 0..7
  const int tau = qb * 4 + wid;
  const int b = bh >> 4, hh = bh & 15;
  const size_t base = (size_t)bh << 16;
  const int qrow = tau * 32 + l31;

  // staging map: thread stages 16B at lds byte a = p*4096 + wid*1024 + lane*16
  // row = a>>7 = p*32 + wid*8 + (lane>>3); c16 = lane&7; src c16' = c16 ^ (row&7)
  const int srow = wid * 8 + (lane >> 3);        // p=0 row; p=1 adds 32 (same &7)
  const int sc16 = (lane & 7) ^ (srow & 7);
  const unsigned short* gk = hk  + base + (size_t)srow * 64 + sc16 * 8;
  const unsigned short* gv = hvt + base + (size_t)srow * 1024 + sc16 * 8;
  const int ldst = wid * 512;                    // wave-uniform dest (elems)

  // Q as B-fragments (col=q=lane&31, k=d=16*ks+8h+j), log2-scale pre-folded
  bf16x8 qf[4];
#pragma unroll
  for (int ks = 0; ks < 4; ++ks)
    qf[ks] = *(const bf16x8*)(hq + base + (size_t)qrow * 64 + ks * 16 + h8);

  f32x16 of0, of1;
#pragma unroll
  for (int r = 0; r < 16; ++r) { of0[r] = 0.f; of1[r] = 0.f; }
  float mrun = -3.0e38f, lrun = 0.f;

  const int nblk = 2 * qb + 2;           // chunks the BLOCK stages
  const int myend = (4 * qb + wid) >> 1; // last chunk this wave computes

  // prologue: stage chunk 0 into buf 0
  gl2lds16(gk,                 &Ks[0][ldst]);
  gl2lds16(gk + 32 * 64,       &Ks[0][2048 + ldst]);
  gl2lds16(gv,                 &Vs[0][ldst]);
  gl2lds16(gv + 32 * 1024,     &Vs[0][2048 + ldst]);

  int cur = 0;
  for (int kt = 0; kt < nblk; ++kt) {
    __syncthreads();   // buf[cur] ready (per-wave vmcnt drained) + prev compute done
    if (kt + 1 < nblk) {
      const int kvb1 = (kt + 1) * 64;
      gl2lds16(gk + (size_t)kvb1 * 64,             &Ks[cur ^ 1][ldst]);
      gl2lds16(gk + (size_t)(kvb1 + 32) * 64,      &Ks[cur ^ 1][2048 + ldst]);
      gl2lds16(gv + kvb1,                          &Vs[cur ^ 1][ldst]);
      gl2lds16(gv + 32 * 1024 + kvb1,              &Vs[cur ^ 1][2048 + ldst]);
    }
    if (kt <= myend) {
      const int kvb = kt * 64;
      // ---- S^T: two 32-kv subtiles from swizzled LDS ----
      f32x16 sa, sb;
#pragma unroll
      for (int r = 0; r < 16; ++r) { sa[r] = 0.f; sb[r] = 0.f; }
      __builtin_amdgcn_s_setprio(1);
#pragma unroll
      for (int ks = 0; ks < 4; ++ks) {
        const int c = ((ks * 2 + h) ^ swz) << 3;
        bf16x8 kfa = *(const bf16x8*)(&Ks[cur][l31 * 64 + c]);
        bf16x8 kfb = *(const bf16x8*)(&Ks[cur][(32 + l31) * 64 + c]);
        sa = __builtin_amdgcn_mfma_f32_32x32x16_bf16(kfa, qf[ks], sa, 0, 0, 0);
        sb = __builtin_amdgcn_mfma_f32_32x32x16_bf16(kfb, qf[ks], sb, 0, 0, 0);
      }
      __builtin_amdgcn_s_setprio(0);
      // causal mask on the diagonal chunk; kv = kvb(+32) + (r&3)+8*(r>>2)+4h
      if (kt == myend) {
#pragma unroll
        for (int r = 0; r < 16; ++r) {
          int kv = kvb + (r & 3) + 8 * (r >> 2) + h4;
          if (kv > qrow) sa[r] = -1.0e30f;
          if (kv + 32 > qrow) sb[r] = -1.0e30f;
        }
      }
      // ---- online softmax in log2 domain ----
      float mx[8];
#pragma unroll
      for (int g = 0; g < 4; ++g) {
        mx[g]     = fmaxf(fmaxf(sa[4 * g], sa[4 * g + 1]), fmaxf(sa[4 * g + 2], sa[4 * g + 3]));
        mx[4 + g] = fmaxf(fmaxf(sb[4 * g], sb[4 * g + 1]), fmaxf(sb[4 * g + 2], sb[4 * g + 3]));
      }
      mx[0] = fmaxf(mx[0], mx[1]); mx[2] = fmaxf(mx[2], mx[3]);
      mx[4] = fmaxf(mx[4], mx[5]); mx[6] = fmaxf(mx[6], mx[7]);
      float mloc = fmaxf(fmaxf(mx[0], mx[2]), fmaxf(mx[4], mx[6]));
      mloc = fmaxf(mloc, __shfl_xor(mloc, 32));
      if (!__all(mloc <= mrun + 8.0f)) {   // defer-max THR=8 (log2 units)
        float mnew = fmaxf(mrun, mloc);
        float alpha = __builtin_amdgcn_exp2f(mrun - mnew);
        mrun = mnew;
        lrun *= alpha;
#pragma unroll
        for (int r = 0; r < 16; ++r) { of0[r] *= alpha; of1[r] *= alpha; }
      }
      // ---- P = exp2(S - m), packed per 16-kv slice ----
      bf16x8 pa[4];
      float lsum = 0.f;
#pragma unroll
      for (int s2 = 0; s2 < 4; ++s2) {
        float p0 = __builtin_amdgcn_exp2f(((s2 < 2) ? sa[8 * s2 + 0] : sb[8 * (s2 - 2) + 0]) - mrun);
        float p1 = __builtin_amdgcn_exp2f(((s2 < 2) ? sa[8 * s2 + 1] : sb[8 * (s2 - 2) + 1]) - mrun);
        float p2 = __builtin_amdgcn_exp2f(((s2 < 2) ? sa[8 * s2 + 2] : sb[8 * (s2 - 2) + 2]) - mrun);
        float p3 = __builtin_amdgcn_exp2f(((s2 < 2) ? sa[8 * s2 + 3] : sb[8 * (s2 - 2) + 3]) - mrun);
        float p4 = __builtin_amdgcn_exp2f(((s2 < 2) ? sa[8 * s2 + 4] : sb[8 * (s2 - 2) + 4]) - mrun);
        float p5 = __builtin_amdgcn_exp2f(((s2 < 2) ? sa[8 * s2 + 5] : sb[8 * (s2 - 2) + 5]) - mrun);
        float p6 = __builtin_amdgcn_exp2f(((s2 < 2) ? sa[8 * s2 + 6] : sb[8 * (s2 - 2) + 6]) - mrun);
        float p7 = __builtin_amdgcn_exp2f(((s2 < 2) ? sa[8 * s2 + 7] : sb[8 * (s2 - 2) + 7]) - mrun);
        lsum += (p0 + p1) + (p2 + p3) + ((p4 + p5) + (p6 + p7));
        uint4 w4 = make_uint4(cvt_pk_bf16(p0, p1), cvt_pk_bf16(p2, p3),
                              cvt_pk_bf16(p4, p5), cvt_pk_bf16(p6, p7));
        pa[s2] = __builtin_bit_cast(bf16x8, w4);
      }
      lsum += __shfl_xor(lsum, 32);
      lrun += lsum;
      // ---- O^T += V^T * P^T; V from swizzled LDS (two 8B reads per frag) ----
      __builtin_amdgcn_s_setprio(1);
#pragma unroll
      for (int s2 = 0; s2 < 4; ++s2) {
        const int c1 = (((2 * s2)     ^ swz) << 3) + h4;
        const int c2 = (((2 * s2 + 1) ^ swz) << 3) + h4;
        uint2 a1 = *(const uint2*)(&Vs[cur][l31 * 64 + c1]);
        uint2 a2 = *(const uint2*)(&Vs[cur][l31 * 64 + c2]);
        uint2 b1 = *(const uint2*)(&Vs[cur][(32 + l31) * 64 + c1]);
        uint2 b2 = *(const uint2*)(&Vs[cur][(32 + l31) * 64 + c2]);
        bf16x8 vf0 = __builtin_bit_cast(bf16x8, make_uint4(a1.x, a1.y, a2.x, a2.y));
        bf16x8 vf1 = __builtin_bit_cast(bf16x8, make_uint4(b1.x, b1.y, b2.x, b2.y));
        of0 = __builtin_amdgcn_mfma_f32_32x32x16_bf16(vf0, pa[s2], of0, 0, 0, 0);
        of1 = __builtin_amdgcn_mfma_f32_32x32x16_bf16(vf1, pa[s2], of1, 0, 0, 0);
      }
      __builtin_amdgcn_s_setprio(0);
    }
    cur ^= 1;
  }

  // ---- write vec: lane owns q-row; d = 8g + 4h + rr (of0), +32 (of1) ----
  float rl = __builtin_amdgcn_rcpf(lrun);
  unsigned short* vout = vec + ((size_t)qrow * 8 + b) * 1024 + hh * 64;
#pragma unroll
  for (int g = 0; g < 4; ++g) {
    ushort4 o;
    o.x = f2bf(of0[g * 4 + 0] * rl); o.y = f2bf(of0[g * 4 + 1] * rl);
    o.z = f2bf(of0[g * 4 + 2] * rl); o.w = f2bf(of0[g * 4 + 3] * rl);
    *(ushort4*)(vout + 8 * g + h4) = o;
    o.x = f2bf(of1[g * 4 + 0] * rl); o.y = f2bf(of1[g * 4 + 1] * rl);
    o.z = f2bf(of1[g * 4 + 2] * rl); o.w = f2bf(of1[g * 4 + 3] * rl);
    *(ushort4*)(vout + 32 + 8 * g + h4) = o;
  }
}

// ---------------- in-place LayerNorm over rows of 1024 fp32 ----------------
__global__ __launch_bounds__(256)
void ln_inplace(float* __restrict__ x, const float* __restrict__ gamma,
                const float* __restrict__ beta)
{
  __shared__ float red[2][4];
  const int tid = threadIdx.x;
  const int lane = tid & 63, wid = tid >> 6;
  const size_t row = blockIdx.x;
  float4 v = *(const float4*)(x + row * 1024 + tid * 4);
  float s = v.x + v.y + v.z + v.w;
  float q = v.x * v.x + v.y * v.y + v.z * v.z + v.w * v.w;
#pragma unroll
  for (int m = 1; m <= 32; m <<= 1) {
    s += __shfl_xor(s, m);
    q += __shfl_xor(q, m);
  }
  if (lane == 0) { red[0][wid] = s; red[1][wid] = q; }
  __syncthreads();
  float ts = red[0][0] + red[0][1] + red[0][2] + red[0][3];
  float tq = red[1][0] + red[1][1] + red[1][2] + red[1][3];
  float mu = ts * (1.0f / 1024.0f);
  float var = tq * (1.0f / 1024.0f) - mu * mu;
  float rs = rsqrtf(var + 1e-5f);
  float4 g  = *(const float4*)(gamma + tid * 4);
  float4 bt = *(const float4*)(beta + tid * 4);
  v.x = (v.x - mu) * rs * g.x + bt.x;
  v.y = (v.y - mu) * rs * g.y + bt.y;
  v.z = (v.z - mu) * rs * g.z + bt.z;
  v.w = (v.w - mu) * rs * g.w + bt.w;
  *(float4*)(x + row * 1024 + tid * 4) = v;
}

extern "C" void kernel_launch(void* const* d_in, const int* in_sizes, int n_in,
                              void* d_out, int out_size, void* d_ws, size_t ws_size,
                              hipStream_t stream) {
  const float* q     = (const float*)d_in[0];
  const float* k     = (const float*)d_in[1];
  const float* v     = (const float*)d_in[2];
  // d_in[3] = attn_mask (causal) -- analytic in-kernel
  const float* Wq    = (const float*)d_in[4];
  const float* Wk    = (const float*)d_in[5];
  const float* Wv    = (const float*)d_in[6];
  const float* Wo    = (const float*)d_in[7];
  const float* gamma = (const float*)d_in[8];
  const float* beta  = (const float*)d_in[9];

  unsigned short* ws = (unsigned short*)d_ws;
  const size_t MSZ = (size_t)8192 * 1024;
  unsigned short* hq   = ws;                 // (B,H,T,DH)
  unsigned short* hk   = ws + MSZ;           // (B,H,T,DH)
  unsigned short* hvt  = ws + 2 * MSZ;       // (B,H,DH,T)
  unsigned short* tmp  = ws + 3 * MSZ;       // v-bf16, then k-bf16
  unsigned short* qb16 = ws + 4 * MSZ;       // q-bf16, then vec
  unsigned short* WqT  = ws + 5 * MSZ;       // 4x [1024][1024] bf16
  unsigned short* WkT  = WqT + 1048576;
  unsigned short* WvT  = WqT + 2097152;
  unsigned short* WoT  = WqT + 3145728;
  float* out = (float*)d_out;

  dim3 bb(256);
  dim3 gg(64, 8);
  wconv4<<<dim3(512, 4), bb, 0, stream>>>(Wq, Wk, Wv, Wo, WqT, WkT, WvT, WoT);

  conv_bf16<<<4096, bb, 0, stream>>>(v, tmp);
  gemm_bf16<1><<<gg, bb, 0, stream>>>(tmp, WvT, hvt);           // V^T

  conv2_bf16<<<dim3(4096, 2), bb, 0, stream>>>(q, k, qb16, tmp);
  gemm_qk<<<dim3(64, 8, 2), bb, 0, stream>>>(qb16, tmp, WqT, WkT, hq, hk);

  flash_attn<<<1024, bb, 0, stream>>>(hq, hk, hvt, qb16);       // vec = qb16

  gemm_bf16<2><<<gg, bb, 0, stream>>>(qb16, WoT, out);
  ln_inplace<<<8192, bb, 0, stream>>>(out, gamma, beta);
}

// Round 9
// 203.952 us; speedup vs baseline: 1.3884x; 1.0326x over previous
//
#include <hip/hip_runtime.h>
#include <hip/hip_bf16.h>

// Shapes fixed by the reference: T=1024, B=8, D=1024, H=16, DH=64. M=T*B=8192.
// Intermediate layouts: hq,hk = (B,H,T,DH) bf16; hvt = (B,H,DH,T) bf16 (V^T);
// vec = row-major (M,1024) bf16 with m = t*8+b.
// Scores are produced in log2-domain: 0.125*log2(e) folded into Wq.
// All GEMM LDS tiles use the T2 XOR swizzle (rule #21): linear LDS dest,
// global SOURCE col16 ^= row&7 (involution), ds_read col16 ^= row&7.

typedef __bf16 bf16x8 __attribute__((ext_vector_type(8)));
typedef float f32x4 __attribute__((ext_vector_type(4)));
typedef float f32x16 __attribute__((ext_vector_type(16)));
typedef unsigned short ushort8_t __attribute__((ext_vector_type(8)));

__device__ __forceinline__ unsigned short f2bf(float f) {
  unsigned int u = __builtin_bit_cast(unsigned int, f);
  u += 0x7FFFu + ((u >> 16) & 1u);   // RNE; finite inputs
  return (unsigned short)(u >> 16);
}

__device__ __forceinline__ unsigned int cvt_pk_bf16(float lo, float hi) {
  unsigned int r;
  asm("v_cvt_pk_bf16_f32 %0, %1, %2" : "=v"(r) : "v"(lo), "v"(hi));
  return r;
}

__device__ __forceinline__ void gl2lds16(const unsigned short* g, unsigned short* l) {
  __builtin_amdgcn_global_load_lds(
      (const __attribute__((address_space(1))) void*)g,
      (__attribute__((address_space(3))) void*)l, 16, 0, 0);
}

// ---------------- Q+K combined GEMM (128x128 tile, swizzled LDS) ------------
// z=0: Aq x Wq -> Cq ; z=1: Ak x Wk -> Ck. Output (B,H,T,DH) bf16.
__global__ __launch_bounds__(256)
void gemm_qk(const unsigned short* __restrict__ Aq, const unsigned short* __restrict__ Ak,
             const unsigned short* __restrict__ Wq, const unsigned short* __restrict__ Wk,
             unsigned short* __restrict__ Cq, unsigned short* __restrict__ Ck)
{
  const int z = blockIdx.z;
  const unsigned short* A  = z ? Ak : Aq;
  const unsigned short* Bt = z ? Wk : Wq;
  unsigned short* C        = z ? Ck : Cq;
  __shared__ __align__(16) unsigned short As[128 * 64];
  __shared__ __align__(16) unsigned short Bs[128 * 64];
  const int tid = threadIdx.x;
  const int lane = tid & 63, wid = tid >> 6;
  const int wr = wid >> 1, wc = wid & 1;
  const int l15 = lane & 15, l4 = lane >> 4;
  const int r7 = l15 & 7;              // read-side row XOR key
  const int bm = blockIdx.x, bn = blockIdx.y;

  f32x4 acc[4][4];
#pragma unroll
  for (int m = 0; m < 4; ++m)
#pragma unroll
    for (int n = 0; n < 4; ++n)
      acc[m][n] = (f32x4){0.f, 0.f, 0.f, 0.f};

  // source swizzle: staged row (tid>>3)+32i (row&7 const over i); c16' = c16^(row&7)
  const int sc16 = (tid & 7) ^ ((tid >> 3) & 7);
  const unsigned short* ga = A  + (size_t)bm * 128 * 1024 + (tid >> 3) * 1024 + sc16 * 8;
  const unsigned short* gb = Bt + (size_t)bn * 128 * 1024 + (tid >> 3) * 1024 + sc16 * 8;
  unsigned short* la = As + wid * 512;   // wave-uniform LDS base; HW adds lane*16B
  unsigned short* lb = Bs + wid * 512;

  for (int kt = 0; kt < 1024; kt += 64) {
    if (kt) __syncthreads();
#pragma unroll
    for (int i = 0; i < 4; ++i) {
      gl2lds16(ga + i * 32 * 1024 + kt, la + i * 2048);
      gl2lds16(gb + i * 32 * 1024 + kt, lb + i * 2048);
    }
    __syncthreads();
#pragma unroll
    for (int kk = 0; kk < 2; ++kk) {
      bf16x8 af[4], bfr[4];
      const int c = ((kk * 4 + l4) ^ r7) << 3;   // swizzled read col
#pragma unroll
      for (int m = 0; m < 4; ++m)
        af[m] = *(const bf16x8*)(As + (wr * 64 + m * 16 + l15) * 64 + c);
#pragma unroll
      for (int n = 0; n < 4; ++n)
        bfr[n] = *(const bf16x8*)(Bs + (wc * 64 + n * 16 + l15) * 64 + c);
#pragma unroll
      for (int m = 0; m < 4; ++m)
#pragma unroll
        for (int n = 0; n < 4; ++n)
          acc[m][n] = __builtin_amdgcn_mfma_f32_16x16x32_bf16(af[m], bfr[n], acc[m][n], 0, 0, 0);
    }
  }

#pragma unroll
  for (int m = 0; m < 4; ++m)
#pragma unroll
    for (int n = 0; n < 4; ++n)
#pragma unroll
      for (int r = 0; r < 4; ++r) {
        int row = bm * 128 + wr * 64 + m * 16 + l4 * 4 + r;   // m = t*8+b
        int col = bn * 128 + wc * 64 + n * 16 + l15;           // h*64+dh
        int t = row >> 3, b = row & 7;
        int h = col >> 6, dh = col & 63;
        size_t base = ((size_t)(b * 16 + h)) << 16;
        C[base + (size_t)t * 64 + dh] = f2bf(acc[m][n][r]);
      }
}

// ---------------- 64x128-tile GEMM (1024 blocks, swizzled LDS) --------------
// A: [8192][1024] bf16. Bt: [1024][1024] bf16 = W^T ([n][k]).
// EPI 1: bf16 out at ((b*16+h)*64+dh)*1024+t   (B,H,DH,T)  [V^T]
// EPI 2: fp32 out row-major [8192][1024]
template<int EPI>
__global__ __launch_bounds__(256)
void gemm_small(const unsigned short* __restrict__ A,
                const unsigned short* __restrict__ Bt,
                void* __restrict__ C)
{
  __shared__ __align__(16) unsigned short As[64 * 64];    // 8 KB
  __shared__ __align__(16) unsigned short Bs[128 * 64];   // 16 KB
  const int tid = threadIdx.x;
  const int lane = tid & 63, wid = tid >> 6;
  const int wr = wid >> 1, wc = wid & 1;
  const int l15 = lane & 15, l4 = lane >> 4;
  const int r7 = l15 & 7;
  const int bm = blockIdx.x, bn = blockIdx.y;

  f32x4 acc[2][4];
#pragma unroll
  for (int m = 0; m < 2; ++m)
#pragma unroll
    for (int n = 0; n < 4; ++n)
      acc[m][n] = (f32x4){0.f, 0.f, 0.f, 0.f};

  const int sc16 = (tid & 7) ^ ((tid >> 3) & 7);
  const unsigned short* ga = A  + (size_t)bm * 64 * 1024  + (tid >> 3) * 1024 + sc16 * 8;
  const unsigned short* gb = Bt + (size_t)bn * 128 * 1024 + (tid >> 3) * 1024 + sc16 * 8;
  unsigned short* la = As + wid * 512;
  unsigned short* lb = Bs + wid * 512;

  for (int kt = 0; kt < 1024; kt += 64) {
    if (kt) __syncthreads();
#pragma unroll
    for (int i = 0; i < 2; ++i)
      gl2lds16(ga + i * 32 * 1024 + kt, la + i * 2048);
#pragma unroll
    for (int i = 0; i < 4; ++i)
      gl2lds16(gb + i * 32 * 1024 + kt, lb + i * 2048);
    __syncthreads();
#pragma unroll
    for (int kk = 0; kk < 2; ++kk) {
      const int c = ((kk * 4 + l4) ^ r7) << 3;
      bf16x8 af[2], bfr[4];
#pragma unroll
      for (int m = 0; m < 2; ++m)
        af[m] = *(const bf16x8*)(As + (wr * 32 + m * 16 + l15) * 64 + c);
#pragma unroll
      for (int n = 0; n < 4; ++n)
        bfr[n] = *(const bf16x8*)(Bs + (wc * 64 + n * 16 + l15) * 64 + c);
#pragma unroll
      for (int m = 0; m < 2; ++m)
#pragma unroll
        for (int n = 0; n < 4; ++n)
          acc[m][n] = __builtin_amdgcn_mfma_f32_16x16x32_bf16(af[m], bfr[n], acc[m][n], 0, 0, 0);
    }
  }

#pragma unroll
  for (int m = 0; m < 2; ++m)
#pragma unroll
    for (int n = 0; n < 4; ++n)
#pragma unroll
      for (int r = 0; r < 4; ++r) {
        int row = bm * 64 + wr * 32 + m * 16 + l4 * 4 + r;   // m = t*8+b
        int col = bn * 128 + wc * 64 + n * 16 + l15;          // h*64+dh
        float v = acc[m][n][r];
        if constexpr (EPI == 2) {
          ((float*)C)[(size_t)row * 1024 + col] = v;
        } else {
          int t = row >> 3, b = row & 7;
          int h = col >> 6, dh = col & 63;
          size_t base = ((size_t)(b * 16 + h)) << 16;
          ((unsigned short*)C)[base + (size_t)dh * 1024 + t] = f2bf(v);
        }
      }
}

// ---------------- fp32 -> bf16 converts ----------------
__global__ __launch_bounds__(256)
void conv_bf16(const float* __restrict__ in, unsigned short* __restrict__ out)
{
  size_t i = ((size_t)blockIdx.x * 256 + threadIdx.x) * 8;
  float4 a = *(const float4*)(in + i);
  float4 b = *(const float4*)(in + i + 4);
  ushort8_t o;
  o[0] = f2bf(a.x); o[1] = f2bf(a.y); o[2] = f2bf(a.z); o[3] = f2bf(a.w);
  o[4] = f2bf(b.x); o[5] = f2bf(b.y); o[6] = f2bf(b.z); o[7] = f2bf(b.w);
  *(ushort8_t*)(out + i) = o;
}

__global__ __launch_bounds__(256)
void conv2_bf16(const float* __restrict__ in0, const float* __restrict__ in1,
                unsigned short* __restrict__ out0, unsigned short* __restrict__ out1)
{
  const float* in = blockIdx.y ? in1 : in0;
  unsigned short* out = blockIdx.y ? out1 : out0;
  size_t i = ((size_t)blockIdx.x * 256 + threadIdx.x) * 8;
  float4 a = *(const float4*)(in + i);
  float4 b = *(const float4*)(in + i + 4);
  ushort8_t o;
  o[0] = f2bf(a.x); o[1] = f2bf(a.y); o[2] = f2bf(a.z); o[3] = f2bf(a.w);
  o[4] = f2bf(b.x); o[5] = f2bf(b.y); o[6] = f2bf(b.z); o[7] = f2bf(b.w);
  *(ushort8_t*)(out + i) = o;
}

// -------- weights: W[k][n] fp32 -> Wt[n][k] bf16 (x4, y-selected) -----------
__global__ __launch_bounds__(256)
void wconv4(const float* __restrict__ W0, const float* __restrict__ W1,
            const float* __restrict__ W2, const float* __restrict__ W3,
            unsigned short* __restrict__ T0, unsigned short* __restrict__ T1,
            unsigned short* __restrict__ T2, unsigned short* __restrict__ T3)
{
  const int y = blockIdx.y;
  const float* W = y == 0 ? W0 : y == 1 ? W1 : y == 2 ? W2 : W3;
  unsigned short* Wt = y == 0 ? T0 : y == 1 ? T1 : y == 2 ? T2 : T3;
  const float scale = (y == 0) ? 0.125f * 1.44269504088896f : 1.0f;
  int id = blockIdx.x * 256 + threadIdx.x;
  int n = id & 1023;
  int k0 = (id >> 10) << 3;
  ushort8_t o;
#pragma unroll
  for (int j = 0; j < 8; ++j)
    o[j] = f2bf(W[(size_t)(k0 + j) * 1024 + n] * scale);
  *(ushort8_t*)(Wt + (size_t)n * 1024 + k0) = o;
}

// ---------------- causal flash attention (LDS-staged K/V, swapped 32x32) ----
// (unchanged from round 8 -- verified)
__global__ __launch_bounds__(256)
void flash_attn(const unsigned short* __restrict__ hq,
                const unsigned short* __restrict__ hk,
                const unsigned short* __restrict__ hvt,
                unsigned short* __restrict__ vec)
{
  __shared__ __align__(16) unsigned short Ks[2][64 * 64];
  __shared__ __align__(16) unsigned short Vs[2][64 * 64];
  const int tid = threadIdx.x;
  const int lane = tid & 63, wid = tid >> 6;
  const int l31 = lane & 31, h = lane >> 5;
  const int h8 = h * 8, h4 = h * 4;
  const int swz = l31 & 7;
  const int bid = blockIdx.x;
  const int xcd = bid & 7;
  const int i = bid >> 3;
  const int bh = (xcd << 4) | (i & 15);
  const int qb = 7 - (i >> 4);
  const int tau = qb * 4 + wid;
  const int b = bh >> 4, hh = bh & 15;
  const size_t base = (size_t)bh << 16;
  const int qrow = tau * 32 + l31;

  const int srow = wid * 8 + (lane >> 3);
  const int sc16 = (lane & 7) ^ (srow & 7);
  const unsigned short* gk = hk  + base + (size_t)srow * 64 + sc16 * 8;
  const unsigned short* gv = hvt + base + (size_t)srow * 1024 + sc16 * 8;
  const int ldst = wid * 512;

  bf16x8 qf[4];
#pragma unroll
  for (int ks = 0; ks < 4; ++ks)
    qf[ks] = *(const bf16x8*)(hq + base + (size_t)qrow * 64 + ks * 16 + h8);

  f32x16 of0, of1;
#pragma unroll
  for (int r = 0; r < 16; ++r) { of0[r] = 0.f; of1[r] = 0.f; }
  float mrun = -3.0e38f, lrun = 0.f;

  const int nblk = 2 * qb + 2;
  const int myend = (4 * qb + wid) >> 1;

  gl2lds16(gk,             &Ks[0][ldst]);
  gl2lds16(gk + 32 * 64,   &Ks[0][2048 + ldst]);
  gl2lds16(gv,             &Vs[0][ldst]);
  gl2lds16(gv + 32 * 1024, &Vs[0][2048 + ldst]);

  int cur = 0;
  for (int kt = 0; kt < nblk; ++kt) {
    __syncthreads();
    if (kt + 1 < nblk) {
      const int kvb1 = (kt + 1) * 64;
      gl2lds16(gk + (size_t)kvb1 * 64,        &Ks[cur ^ 1][ldst]);
      gl2lds16(gk + (size_t)(kvb1 + 32) * 64, &Ks[cur ^ 1][2048 + ldst]);
      gl2lds16(gv + kvb1,                     &Vs[cur ^ 1][ldst]);
      gl2lds16(gv + 32 * 1024 + kvb1,         &Vs[cur ^ 1][2048 + ldst]);
    }
    if (kt <= myend) {
      const int kvb = kt * 64;
      f32x16 sa, sb;
#pragma unroll
      for (int r = 0; r < 16; ++r) { sa[r] = 0.f; sb[r] = 0.f; }
      __builtin_amdgcn_s_setprio(1);
#pragma unroll
      for (int ks = 0; ks < 4; ++ks) {
        const int c = ((ks * 2 + h) ^ swz) << 3;
        bf16x8 kfa = *(const bf16x8*)(&Ks[cur][l31 * 64 + c]);
        bf16x8 kfb = *(const bf16x8*)(&Ks[cur][(32 + l31) * 64 + c]);
        sa = __builtin_amdgcn_mfma_f32_32x32x16_bf16(kfa, qf[ks], sa, 0, 0, 0);
        sb = __builtin_amdgcn_mfma_f32_32x32x16_bf16(kfb, qf[ks], sb, 0, 0, 0);
      }
      __builtin_amdgcn_s_setprio(0);
      if (kt == myend) {
#pragma unroll
        for (int r = 0; r < 16; ++r) {
          int kv = kvb + (r & 3) + 8 * (r >> 2) + h4;
          if (kv > qrow) sa[r] = -1.0e30f;
          if (kv + 32 > qrow) sb[r] = -1.0e30f;
        }
      }
      float mx[8];
#pragma unroll
      for (int g = 0; g < 4; ++g) {
        mx[g]     = fmaxf(fmaxf(sa[4 * g], sa[4 * g + 1]), fmaxf(sa[4 * g + 2], sa[4 * g + 3]));
        mx[4 + g] = fmaxf(fmaxf(sb[4 * g], sb[4 * g + 1]), fmaxf(sb[4 * g + 2], sb[4 * g + 3]));
      }
      mx[0] = fmaxf(mx[0], mx[1]); mx[2] = fmaxf(mx[2], mx[3]);
      mx[4] = fmaxf(mx[4], mx[5]); mx[6] = fmaxf(mx[6], mx[7]);
      float mloc = fmaxf(fmaxf(mx[0], mx[2]), fmaxf(mx[4], mx[6]));
      mloc = fmaxf(mloc, __shfl_xor(mloc, 32));
      if (!__all(mloc <= mrun + 8.0f)) {
        float mnew = fmaxf(mrun, mloc);
        float alpha = __builtin_amdgcn_exp2f(mrun - mnew);
        mrun = mnew;
        lrun *= alpha;
#pragma unroll
        for (int r = 0; r < 16; ++r) { of0[r] *= alpha; of1[r] *= alpha; }
      }
      bf16x8 pa[4];
      float lsum = 0.f;
#pragma unroll
      for (int s2 = 0; s2 < 4; ++s2) {
        float p0 = __builtin_amdgcn_exp2f(((s2 < 2) ? sa[8 * s2 + 0] : sb[8 * (s2 - 2) + 0]) - mrun);
        float p1 = __builtin_amdgcn_exp2f(((s2 < 2) ? sa[8 * s2 + 1] : sb[8 * (s2 - 2) + 1]) - mrun);
        float p2 = __builtin_amdgcn_exp2f(((s2 < 2) ? sa[8 * s2 + 2] : sb[8 * (s2 - 2) + 2]) - mrun);
        float p3 = __builtin_amdgcn_exp2f(((s2 < 2) ? sa[8 * s2 + 3] : sb[8 * (s2 - 2) + 3]) - mrun);
        float p4 = __builtin_amdgcn_exp2f(((s2 < 2) ? sa[8 * s2 + 4] : sb[8 * (s2 - 2) + 4]) - mrun);
        float p5 = __builtin_amdgcn_exp2f(((s2 < 2) ? sa[8 * s2 + 5] : sb[8 * (s2 - 2) + 5]) - mrun);
        float p6 = __builtin_amdgcn_exp2f(((s2 < 2) ? sa[8 * s2 + 6] : sb[8 * (s2 - 2) + 6]) - mrun);
        float p7 = __builtin_amdgcn_exp2f(((s2 < 2) ? sa[8 * s2 + 7] : sb[8 * (s2 - 2) + 7]) - mrun);
        lsum += (p0 + p1) + (p2 + p3) + ((p4 + p5) + (p6 + p7));
        uint4 w4 = make_uint4(cvt_pk_bf16(p0, p1), cvt_pk_bf16(p2, p3),
                              cvt_pk_bf16(p4, p5), cvt_pk_bf16(p6, p7));
        pa[s2] = __builtin_bit_cast(bf16x8, w4);
      }
      lsum += __shfl_xor(lsum, 32);
      lrun += lsum;
      __builtin_amdgcn_s_setprio(1);
#pragma unroll
      for (int s2 = 0; s2 < 4; ++s2) {
        const int c1 = (((2 * s2)     ^ swz) << 3) + h4;
        const int c2 = (((2 * s2 + 1) ^ swz) << 3) + h4;
        uint2 a1 = *(const uint2*)(&Vs[cur][l31 * 64 + c1]);
        uint2 a2 = *(const uint2*)(&Vs[cur][l31 * 64 + c2]);
        uint2 b1 = *(const uint2*)(&Vs[cur][(32 + l31) * 64 + c1]);
        uint2 b2 = *(const uint2*)(&Vs[cur][(32 + l31) * 64 + c2]);
        bf16x8 vf0 = __builtin_bit_cast(bf16x8, make_uint4(a1.x, a1.y, a2.x, a2.y));
        bf16x8 vf1 = __builtin_bit_cast(bf16x8, make_uint4(b1.x, b1.y, b2.x, b2.y));
        of0 = __builtin_amdgcn_mfma_f32_32x32x16_bf16(vf0, pa[s2], of0, 0, 0, 0);
        of1 = __builtin_amdgcn_mfma_f32_32x32x16_bf16(vf1, pa[s2], of1, 0, 0, 0);
      }
      __builtin_amdgcn_s_setprio(0);
    }
    cur ^= 1;
  }

  float rl = __builtin_amdgcn_rcpf(lrun);
  unsigned short* vout = vec + ((size_t)qrow * 8 + b) * 1024 + hh * 64;
#pragma unroll
  for (int g = 0; g < 4; ++g) {
    ushort4 o;
    o.x = f2bf(of0[g * 4 + 0] * rl); o.y = f2bf(of0[g * 4 + 1] * rl);
    o.z = f2bf(of0[g * 4 + 2] * rl); o.w = f2bf(of0[g * 4 + 3] * rl);
    *(ushort4*)(vout + 8 * g + h4) = o;
    o.x = f2bf(of1[g * 4 + 0] * rl); o.y = f2bf(of1[g * 4 + 1] * rl);
    o.z = f2bf(of1[g * 4 + 2] * rl); o.w = f2bf(of1[g * 4 + 3] * rl);
    *(ushort4*)(vout + 32 + 8 * g + h4) = o;
  }
}

// ---------------- in-place LayerNorm over rows of 1024 fp32 ----------------
__global__ __launch_bounds__(256)
void ln_inplace(float* __restrict__ x, const float* __restrict__ gamma,
                const float* __restrict__ beta)
{
  __shared__ float red[2][4];
  const int tid = threadIdx.x;
  const int lane = tid & 63, wid = tid >> 6;
  const size_t row = blockIdx.x;
  float4 v = *(const float4*)(x + row * 1024 + tid * 4);
  float s = v.x + v.y + v.z + v.w;
  float q = v.x * v.x + v.y * v.y + v.z * v.z + v.w * v.w;
#pragma unroll
  for (int m = 1; m <= 32; m <<= 1) {
    s += __shfl_xor(s, m);
    q += __shfl_xor(q, m);
  }
  if (lane == 0) { red[0][wid] = s; red[1][wid] = q; }
  __syncthreads();
  float ts = red[0][0] + red[0][1] + red[0][2] + red[0][3];
  float tq = red[1][0] + red[1][1] + red[1][2] + red[1][3];
  float mu = ts * (1.0f / 1024.0f);
  float var = tq * (1.0f / 1024.0f) - mu * mu;
  float rs = rsqrtf(var + 1e-5f);
  float4 g  = *(const float4*)(gamma + tid * 4);
  float4 bt = *(const float4*)(beta + tid * 4);
  v.x = (v.x - mu) * rs * g.x + bt.x;
  v.y = (v.y - mu) * rs * g.y + bt.y;
  v.z = (v.z - mu) * rs * g.z + bt.z;
  v.w = (v.w - mu) * rs * g.w + bt.w;
  *(float4*)(x + row * 1024 + tid * 4) = v;
}

extern "C" void kernel_launch(void* const* d_in, const int* in_sizes, int n_in,
                              void* d_out, int out_size, void* d_ws, size_t ws_size,
                              hipStream_t stream) {
  const float* q     = (const float*)d_in[0];
  const float* k     = (const float*)d_in[1];
  const float* v     = (const float*)d_in[2];
  // d_in[3] = attn_mask (causal) -- analytic in-kernel
  const float* Wq    = (const float*)d_in[4];
  const float* Wk    = (const float*)d_in[5];
  const float* Wv    = (const float*)d_in[6];
  const float* Wo    = (const float*)d_in[7];
  const float* gamma = (const float*)d_in[8];
  const float* beta  = (const float*)d_in[9];

  unsigned short* ws = (unsigned short*)d_ws;
  const size_t MSZ = (size_t)8192 * 1024;
  unsigned short* hq   = ws;                 // (B,H,T,DH)
  unsigned short* hk   = ws + MSZ;           // (B,H,T,DH)
  unsigned short* hvt  = ws + 2 * MSZ;       // (B,H,DH,T)
  unsigned short* tmp  = ws + 3 * MSZ;       // v-bf16, then k-bf16
  unsigned short* qb16 = ws + 4 * MSZ;       // q-bf16, then vec
  unsigned short* WqT  = ws + 5 * MSZ;       // 4x [1024][1024] bf16
  unsigned short* WkT  = WqT + 1048576;
  unsigned short* WvT  = WqT + 2097152;
  unsigned short* WoT  = WqT + 3145728;
  float* out = (float*)d_out;

  dim3 bb(256);
  wconv4<<<dim3(512, 4), bb, 0, stream>>>(Wq, Wk, Wv, Wo, WqT, WkT, WvT, WoT);

  conv_bf16<<<4096, bb, 0, stream>>>(v, tmp);
  gemm_small<1><<<dim3(128, 8), bb, 0, stream>>>(tmp, WvT, hvt);   // V^T

  conv2_bf16<<<dim3(4096, 2), bb, 0, stream>>>(q, k, qb16, tmp);
  gemm_qk<<<dim3(64, 8, 2), bb, 0, stream>>>(qb16, tmp, WqT, WkT, hq, hk);

  flash_attn<<<1024, bb, 0, stream>>>(hq, hk, hvt, qb16);          // vec = qb16

  gemm_small<2><<<dim3(128, 8), bb, 0, stream>>>(qb16, WoT, out);
  ln_inplace<<<8192, bb, 0, stream>>>(out, gamma, beta);
}